// Round 6
// baseline (120.357 us; speedup 1.0000x reference)
//
#include <hip/hip_runtime.h>
#include <hip/hip_bf16.h>
#include <math.h>
#include <stdint.h>

constexpr int Nn = 4096, Kk = 32, Hh = 256;
constexpr int Mm = 8 * Nn;          // 32768 rows

typedef float  f32x4 __attribute__((ext_vector_type(4)));
typedef short  s16x8 __attribute__((ext_vector_type(8)));

static __device__ __forceinline__ ushort f2bf(float f) {
  uint32_t u = __float_as_uint(f);
  u += 0x7FFF + ((u >> 16) & 1);
  return (ushort)(u >> 16);
}
static __device__ __forceinline__ float bf2f(ushort s) {
  return __uint_as_float(((uint32_t)s) << 16);
}
static __device__ __forceinline__ void gl_lds16(const ushort* g, ushort* l) {
  __builtin_amdgcn_global_load_lds(
      (const __attribute__((address_space(1))) void*)g,
      (__attribute__((address_space(3))) void*)l, 16, 0, 0);
}
// gelu(x) ~= x - x/(e^y + 1),  y = x*(2c + 2c*0.044715*x^2), c = 0.79788456
static __device__ __forceinline__ float gelu_t(float x) {
  float u = x * x;
  float y = x * (1.5957691216f + 0.0713548162726f * u);
  float t = __expf(y);
  return x - x * __builtin_amdgcn_rcpf(t + 1.0f);
}

// ---------------- idx dtype detector ----------------
__global__ void detect_idx(const int* __restrict__ p, int* __restrict__ flag) {
  int t = threadIdx.x;
  unsigned long long b = __ballot(p[2 * t + 1] != 0);
  if (t == 0) *flag = (b != 0ULL) ? 1 : 0;  // 1 = int32, 0 = int64
}

// ---------------- prep: Wcat = [Ws; Wn] bf16, row-major [512][256] ----------
__global__ __launch_bounds__(256) void prep_w(const float* __restrict__ Ws,
                                              const float* __restrict__ Wn,
                                              ushort* __restrict__ Wc) {
  int i = blockIdx.x * 256 + threadIdx.x;      // 32768 threads, 4 elems each
  int j  = i >> 6;
  int k4 = i & 63;
  const float* src = (j < 256) ? (Ws + (size_t)j * 256 + k4 * 4)
                               : (Wn + (size_t)(j - 256) * 256 + k4 * 4);
  float4 v = *reinterpret_cast<const float4*>(src);
  ushort4 o = { f2bf(v.x), f2bf(v.y), f2bf(v.z), f2bf(v.w) };
  reinterpret_cast<ushort4*>(Wc)[i] = o;
}

// ---------------- gemm1: [hs|hn] = h @ Wcat^T, bf16 out, no epilogue -------
__global__ __launch_bounds__(512, 4) void gemm1(const float* __restrict__ h,
                                                const ushort* __restrict__ Wc,
                                                ushort* __restrict__ hs,
                                                ushort* __restrict__ hn) {
  __shared__ ushort lA[2][64 * 64];    // 2 x 8 KB
  __shared__ ushort lB[2][256 * 64];   // 2 x 32 KB
  const int tid = threadIdx.x, wid = tid >> 6, lane = tid & 63;
  const int wr = wid >> 1, wc = wid & 1;

  const int blk = blockIdx.x;
  const int b = blk & 7, t = blk >> 3;
  const int nblk = t & 1, mblk = t >> 1;
  const int m0 = b * Nn + mblk * 64;
  const ushort* Wbase = Wc + (size_t)nblk * 256 * 256;

  f32x4 acc[8];
  #pragma unroll
  for (int j = 0; j < 8; ++j) acc[j] = f32x4{0.f, 0.f, 0.f, 0.f};

  float4 a0, a1;
  const int ar = tid >> 3, as = tid & 7;             // A stage: row, slot
  auto aload = [&](int kt) {
    const float* src = h + (size_t)(m0 + ar) * 256 + kt * 64 + as * 8;
    a0 = *reinterpret_cast<const float4*>(src);
    a1 = *reinterpret_cast<const float4*>(src + 4);
  };
  auto awrite = [&](int buf) {
    s16x8 u = { (short)f2bf(a0.x), (short)f2bf(a0.y), (short)f2bf(a0.z),
                (short)f2bf(a0.w), (short)f2bf(a1.x), (short)f2bf(a1.y),
                (short)f2bf(a1.z), (short)f2bf(a1.w) };
    *reinterpret_cast<s16x8*>(&lA[buf][ar * 64 + ((as ^ (ar & 7)) << 3)]) = u;
  };
  auto bstage = [&](int buf, int kt) {
    #pragma unroll
    for (int c = 0; c < 4; ++c) {
      int ch = wid + c * 8;
      int r = ch * 8 + (lane >> 3);
      int s = (lane & 7) ^ (r & 7);
      gl_lds16(Wbase + (size_t)r * 256 + kt * 64 + s * 8, &lB[buf][ch * 512]);
    }
  };

  aload(0);
  bstage(0, 0);
  awrite(0);
  __syncthreads();

  int buf = 0;
  for (int kt = 0; kt < 4; ++kt) {
    if (kt < 3) { aload(kt + 1); bstage(buf ^ 1, kt + 1); }
    #pragma unroll
    for (int kk = 0; kk < 2; ++kk) {
      const int ks = kk * 4 + (lane >> 4);
      const int ra = wr * 16 + (lane & 15);
      s16x8 af = *reinterpret_cast<const s16x8*>(
          &lA[buf][ra * 64 + ((ks ^ (ra & 7)) << 3)]);
      s16x8 bfr[8];
      #pragma unroll
      for (int nj = 0; nj < 8; ++nj) {
        int rb = wc * 128 + nj * 16 + (lane & 15);
        bfr[nj] = *reinterpret_cast<const s16x8*>(
            &lB[buf][rb * 64 + ((ks ^ (rb & 7)) << 3)]);
      }
      #pragma unroll
      for (int nj = 0; nj < 8; ++nj)
        acc[nj] = __builtin_amdgcn_mfma_f32_16x16x32_bf16(af, bfr[nj],
                                                          acc[nj], 0, 0, 0);
    }
    if (kt < 3) awrite(buf ^ 1);
    __syncthreads();
    buf ^= 1;
  }

  ushort* dst = (nblk == 0) ? hs : hn;
  #pragma unroll
  for (int nj = 0; nj < 8; ++nj)
    #pragma unroll
    for (int jj = 0; jj < 4; ++jj) {
      int row = wr * 16 + (lane >> 4) * 4 + jj;
      int col = wc * 128 + nj * 16 + (lane & 15);
      dst[(size_t)(m0 + row) * 256 + col] = f2bf(acc[nj][jj]);
    }
}

// ---------------- k2: out = LN(gelu(hs[m] + sum_k w * hn[idx_k])) ----------
// 8 rows/block (one per 32-lane half-wave). CONTIGUOUS batch mapping: blocks
// [b*512, b*512+512) all work batch b, so the active hn slice (2 MB) is
// L2-resident under ANY blockIdx->XCD dispatch granularity (the &7 pinning
// broke at this grid shape: FETCH 20.5 -> 146 MB). Per-block idx/w staged in
// LDS, uniform ds_read_b128 metadata broadcast, 8-deep named gather prefetch.
__global__ __launch_bounds__(256, 4) void k2(const ushort* __restrict__ hs,
                                             const ushort* __restrict__ hn,
                                             const void* __restrict__ idx,
                                             const float* __restrict__ w,
                                             const float* __restrict__ gamma,
                                             const float* __restrict__ beta,
                                             float* __restrict__ out,
                                             const int* __restrict__ flag) {
  __shared__ int   ii[256];
  __shared__ float wf[256];
  const int tid = threadIdx.x, l5 = tid & 31;
  const int blk = blockIdx.x;
  const int b  = blk >> 9;                      // contiguous batch mapping
  const int m0 = b * Nn + (blk & 511) * 8;
  const int m  = m0 + (tid >> 5);
  const int is32 = *flag;

  // early long-latency loads (consumed only in the epilogue)
  s16x8 hv = *reinterpret_cast<const s16x8*>(hs + (size_t)m * Hh + l5 * 8);
  float4 gm0 = reinterpret_cast<const float4*>(gamma)[l5 * 2];
  float4 gm1 = reinterpret_cast<const float4*>(gamma)[l5 * 2 + 1];
  float4 bt0 = reinterpret_cast<const float4*>(beta)[l5 * 2];
  float4 bt1 = reinterpret_cast<const float4*>(beta)[l5 * 2 + 1];

  // stage 8 rows x 32 (idx, w) into LDS, coalesced
  {
    size_t base = (size_t)m0 * Kk + tid;
    ii[tid] = is32 ? ((const int*)idx)[base]
                   : (int)((const long long*)idx)[base];
    wf[tid] = w[base];
  }
  __syncthreads();

  const ushort* hnb = hn + (size_t)b * Nn * Hh;
  const int rb8 = (tid >> 5) * 32;   // this half-wave's row offset in ii/wf

  auto ld = [&](int r) -> s16x8 {
    return *reinterpret_cast<const s16x8*>(hnb + ((size_t)r << 8) + (l5 << 3));
  };

  f32x4 aA0{0,0,0,0}, aA1{0,0,0,0}, aB0{0,0,0,0}, aB1{0,0,0,0};
  s16x8 n0, n1, n2, n3, n4, n5, n6, n7;
  float4 wa, wb;

#define LOADG(g) { \
    int4 ia = *reinterpret_cast<const int4*>(&ii[rb8 + (g) * 8]); \
    int4 ib = *reinterpret_cast<const int4*>(&ii[rb8 + (g) * 8 + 4]); \
    wa = *reinterpret_cast<const float4*>(&wf[rb8 + (g) * 8]); \
    wb = *reinterpret_cast<const float4*>(&wf[rb8 + (g) * 8 + 4]); \
    n0 = ld(ia.x); n1 = ld(ia.y); n2 = ld(ia.z); n3 = ld(ia.w); \
    n4 = ld(ib.x); n5 = ld(ib.y); n6 = ld(ib.z); n7 = ld(ib.w); }

#define CONSA(q, wt) { \
    aA0[0] += wt * bf2f((ushort)q[0]); aA0[1] += wt * bf2f((ushort)q[1]); \
    aA0[2] += wt * bf2f((ushort)q[2]); aA0[3] += wt * bf2f((ushort)q[3]); \
    aA1[0] += wt * bf2f((ushort)q[4]); aA1[1] += wt * bf2f((ushort)q[5]); \
    aA1[2] += wt * bf2f((ushort)q[6]); aA1[3] += wt * bf2f((ushort)q[7]); }
#define CONSB(q, wt) { \
    aB0[0] += wt * bf2f((ushort)q[0]); aB0[1] += wt * bf2f((ushort)q[1]); \
    aB0[2] += wt * bf2f((ushort)q[2]); aB0[3] += wt * bf2f((ushort)q[3]); \
    aB1[0] += wt * bf2f((ushort)q[4]); aB1[1] += wt * bf2f((ushort)q[5]); \
    aB1[2] += wt * bf2f((ushort)q[6]); aB1[3] += wt * bf2f((ushort)q[7]); }

  LOADG(0);
  #pragma unroll
  for (int g = 0; g < 4; ++g) {
    s16x8 q0 = n0, q1 = n1, q2 = n2, q3 = n3;
    s16x8 q4 = n4, q5 = n5, q6 = n6, q7 = n7;
    float4 va = wa, vb = wb;
    if (g < 3) LOADG(g + 1);
    CONSA(q0, va.x); CONSB(q1, va.y); CONSA(q2, va.z); CONSB(q3, va.w);
    CONSA(q4, vb.x); CONSB(q5, vb.y); CONSA(q6, vb.z); CONSB(q7, vb.w);
  }
#undef LOADG
#undef CONSA
#undef CONSB

  float g[8];
  #pragma unroll
  for (int j = 0; j < 4; ++j) {
    g[j]     = gelu_t(aA0[j] + aB0[j] + bf2f((ushort)hv[j]));
    g[j + 4] = gelu_t(aA1[j] + aB1[j] + bf2f((ushort)hv[j + 4]));
  }

  float sv = 0.f, qv = 0.f;
  #pragma unroll
  for (int j = 0; j < 8; ++j) { sv += g[j]; qv += g[j] * g[j]; }
  #pragma unroll
  for (int msk = 16; msk >= 1; msk >>= 1) {   // reduce within the 32-lane half
    sv += __shfl_xor(sv, msk, 64);
    qv += __shfl_xor(qv, msk, 64);
  }
  float mean = sv * (1.0f / 256.0f);
  float var  = qv * (1.0f / 256.0f) - mean * mean;
  float inv  = rsqrtf(var + 1e-5f);

  float4 o0, o1;
  o0.x = (g[0] - mean) * inv * gm0.x + bt0.x;
  o0.y = (g[1] - mean) * inv * gm0.y + bt0.y;
  o0.z = (g[2] - mean) * inv * gm0.z + bt0.z;
  o0.w = (g[3] - mean) * inv * gm0.w + bt0.w;
  o1.x = (g[4] - mean) * inv * gm1.x + bt1.x;
  o1.y = (g[5] - mean) * inv * gm1.y + bt1.y;
  o1.z = (g[6] - mean) * inv * gm1.z + bt1.z;
  o1.w = (g[7] - mean) * inv * gm1.w + bt1.w;
  float4* op = reinterpret_cast<float4*>(out + (size_t)m * Hh + l5 * 8);
  op[0] = o0;
  op[1] = o1;
}

extern "C" void kernel_launch(void* const* d_in, const int* in_sizes, int n_in,
                              void* d_out, int out_size, void* d_ws, size_t ws_size,
                              hipStream_t stream) {
  const float* h     = (const float*)d_in[0];
  const void*  idx   = d_in[1];
  const float* w     = (const float*)d_in[2];
  const float* Ws    = (const float*)d_in[3];
  const float* Wn    = (const float*)d_in[4];
  const float* gamma = (const float*)d_in[5];
  const float* beta  = (const float*)d_in[6];
  float* out = (float*)d_out;

  ushort* hs = (ushort*)d_ws;                       // 16 MB
  ushort* hn = hs + (size_t)Mm * Hh;                // 16 MB
  ushort* Wc = hn + (size_t)Mm * Hh;                // 256 KB
  int* flag  = (int*)(Wc + 512 * 256);

  detect_idx<<<1, 64, 0, stream>>>((const int*)idx, flag);
  prep_w<<<128, 256, 0, stream>>>(Ws, Wn, Wc);
  gemm1<<<1024, 512, 0, stream>>>(h, Wc, hs, hn);
  k2<<<4096, 256, 0, stream>>>(hs, hn, idx, w, gamma, beta, out, flag);
}

// Round 7
// 77.564 us; speedup vs baseline: 1.5517x; 1.5517x over previous
//
#include <hip/hip_runtime.h>
#include <hip/hip_bf16.h>
#include <math.h>
#include <stdint.h>

constexpr int Nn = 4096, Kk = 32, Hh = 256;
constexpr int Mm = 8 * Nn;          // 32768 rows

typedef float  f32x4 __attribute__((ext_vector_type(4)));
typedef short  s16x8 __attribute__((ext_vector_type(8)));

static __device__ __forceinline__ ushort f2bf(float f) {
  uint32_t u = __float_as_uint(f);
  u += 0x7FFF + ((u >> 16) & 1);
  return (ushort)(u >> 16);
}
static __device__ __forceinline__ float bf2f(ushort s) {
  return __uint_as_float(((uint32_t)s) << 16);
}
static __device__ __forceinline__ void gl_lds16(const ushort* g, ushort* l) {
  __builtin_amdgcn_global_load_lds(
      (const __attribute__((address_space(1))) void*)g,
      (__attribute__((address_space(3))) void*)l, 16, 0, 0);
}
// gelu(x) ~= x - x/(e^y + 1),  y = x*(2c + 2c*0.044715*x^2), c = 0.79788456
static __device__ __forceinline__ float gelu_t(float x) {
  float u = x * x;
  float y = x * (1.5957691216f + 0.0713548162726f * u);
  float t = __expf(y);
  return x - x * __builtin_amdgcn_rcpf(t + 1.0f);
}

// ---------------- idx dtype detector ----------------
__global__ void detect_idx(const int* __restrict__ p, int* __restrict__ flag) {
  int t = threadIdx.x;
  unsigned long long b = __ballot(p[2 * t + 1] != 0);
  if (t == 0) *flag = (b != 0ULL) ? 1 : 0;  // 1 = int32, 0 = int64
}

// ---------------- prep: Wcat = [Ws; Wn] bf16, row-major [512][256] ----------
__global__ __launch_bounds__(256) void prep_w(const float* __restrict__ Ws,
                                              const float* __restrict__ Wn,
                                              ushort* __restrict__ Wc) {
  int i = blockIdx.x * 256 + threadIdx.x;      // 32768 threads, 4 elems each
  int j  = i >> 6;
  int k4 = i & 63;
  const float* src = (j < 256) ? (Ws + (size_t)j * 256 + k4 * 4)
                               : (Wn + (size_t)(j - 256) * 256 + k4 * 4);
  float4 v = *reinterpret_cast<const float4*>(src);
  ushort4 o = { f2bf(v.x), f2bf(v.y), f2bf(v.z), f2bf(v.w) };
  reinterpret_cast<ushort4*>(Wc)[i] = o;
}

// ---------------- gemm1: [hs|hn] = h @ Wcat^T, bf16 out, no epilogue -------
__global__ __launch_bounds__(512, 4) void gemm1(const float* __restrict__ h,
                                                const ushort* __restrict__ Wc,
                                                ushort* __restrict__ hs,
                                                ushort* __restrict__ hn) {
  __shared__ ushort lA[2][64 * 64];    // 2 x 8 KB
  __shared__ ushort lB[2][256 * 64];   // 2 x 32 KB
  const int tid = threadIdx.x, wid = tid >> 6, lane = tid & 63;
  const int wr = wid >> 1, wc = wid & 1;

  const int blk = blockIdx.x;
  const int b = blk & 7, t = blk >> 3;
  const int nblk = t & 1, mblk = t >> 1;
  const int m0 = b * Nn + mblk * 64;
  const ushort* Wbase = Wc + (size_t)nblk * 256 * 256;

  f32x4 acc[8];
  #pragma unroll
  for (int j = 0; j < 8; ++j) acc[j] = f32x4{0.f, 0.f, 0.f, 0.f};

  float4 a0, a1;
  const int ar = tid >> 3, as = tid & 7;             // A stage: row, slot
  auto aload = [&](int kt) {
    const float* src = h + (size_t)(m0 + ar) * 256 + kt * 64 + as * 8;
    a0 = *reinterpret_cast<const float4*>(src);
    a1 = *reinterpret_cast<const float4*>(src + 4);
  };
  auto awrite = [&](int buf) {
    s16x8 u = { (short)f2bf(a0.x), (short)f2bf(a0.y), (short)f2bf(a0.z),
                (short)f2bf(a0.w), (short)f2bf(a1.x), (short)f2bf(a1.y),
                (short)f2bf(a1.z), (short)f2bf(a1.w) };
    *reinterpret_cast<s16x8*>(&lA[buf][ar * 64 + ((as ^ (ar & 7)) << 3)]) = u;
  };
  auto bstage = [&](int buf, int kt) {
    #pragma unroll
    for (int c = 0; c < 4; ++c) {
      int ch = wid + c * 8;
      int r = ch * 8 + (lane >> 3);
      int s = (lane & 7) ^ (r & 7);
      gl_lds16(Wbase + (size_t)r * 256 + kt * 64 + s * 8, &lB[buf][ch * 512]);
    }
  };

  aload(0);
  bstage(0, 0);
  awrite(0);
  __syncthreads();

  int buf = 0;
  for (int kt = 0; kt < 4; ++kt) {
    if (kt < 3) { aload(kt + 1); bstage(buf ^ 1, kt + 1); }
    #pragma unroll
    for (int kk = 0; kk < 2; ++kk) {
      const int ks = kk * 4 + (lane >> 4);
      const int ra = wr * 16 + (lane & 15);
      s16x8 af = *reinterpret_cast<const s16x8*>(
          &lA[buf][ra * 64 + ((ks ^ (ra & 7)) << 3)]);
      s16x8 bfr[8];
      #pragma unroll
      for (int nj = 0; nj < 8; ++nj) {
        int rb = wc * 128 + nj * 16 + (lane & 15);
        bfr[nj] = *reinterpret_cast<const s16x8*>(
            &lB[buf][rb * 64 + ((ks ^ (rb & 7)) << 3)]);
      }
      #pragma unroll
      for (int nj = 0; nj < 8; ++nj)
        acc[nj] = __builtin_amdgcn_mfma_f32_16x16x32_bf16(af, bfr[nj],
                                                          acc[nj], 0, 0, 0);
    }
    if (kt < 3) awrite(buf ^ 1);
    __syncthreads();
    buf ^= 1;
  }

  ushort* dst = (nblk == 0) ? hs : hn;
  #pragma unroll
  for (int nj = 0; nj < 8; ++nj)
    #pragma unroll
    for (int jj = 0; jj < 4; ++jj) {
      int row = wr * 16 + (lane >> 4) * 4 + jj;
      int col = wc * 128 + nj * 16 + (lane & 15);
      dst[(size_t)(m0 + row) * 256 + col] = f2bf(acc[nj][jj]);
    }
}

// ---------------- k2: out = LN(gelu(hs[m] + sum_k w * hn[idx_k])) ----------
// EXACT round-4 shape (proven FETCH=20.5MB: grid 2048 x 512 thr, 16 rows/blk,
// one row per 32-lane half-wave, &7 batch map, 4-deep named prefetch, dual
// acc banks). Single change vs R4: idx/w metadata staged once in LDS and read
// per group via 2 uniform-address ds_read_b128 (broadcast) instead of 8
// ds_bpermute __shfl ops on the critical path of every gather group.
__global__ __launch_bounds__(512, 4) void k2(const ushort* __restrict__ hs,
                                             const ushort* __restrict__ hn,
                                             const void* __restrict__ idx,
                                             const float* __restrict__ w,
                                             const float* __restrict__ gamma,
                                             const float* __restrict__ beta,
                                             float* __restrict__ out,
                                             const int* __restrict__ flag) {
  __shared__ int   ii[512];
  __shared__ float wf[512];
  const int tid = threadIdx.x, wv = tid >> 6, lane = tid & 63;
  const int hw = lane >> 5, l5 = lane & 31;
  const int b = blockIdx.x & 7;                       // batch -> XCD pin (R4)
  const int m0 = b * Nn + (blockIdx.x >> 3) * 16;     // 16 rows/block
  const int m  = m0 + wv * 2 + hw;
  const int is32 = *flag;

  // stage 16 rows x 32 (idx, w) into LDS, coalesced
  {
    size_t base = (size_t)m0 * Kk + tid;
    ii[tid] = is32 ? ((const int*)idx)[base]
                   : (int)((const long long*)idx)[base];
    wf[tid] = w[base];
  }
  __syncthreads();

  const ushort* hnb = hn + (size_t)b * Nn * Hh;
  const int rb = (wv * 2 + hw) * 32;   // this half-wave's metadata offset

  auto ld = [&](int r) -> s16x8 {
    return *reinterpret_cast<const s16x8*>(hnb + ((size_t)r << 8) + (l5 << 3));
  };

  f32x4 aA0{0,0,0,0}, aA1{0,0,0,0}, aB0{0,0,0,0}, aB1{0,0,0,0};
  s16x8 n0, n1, n2, n3;
  int4   ia;
  float4 wa;

#define LOADG(g) { \
    ia = *reinterpret_cast<const int4*>(&ii[rb + (g) * 4]); \
    wa = *reinterpret_cast<const float4*>(&wf[rb + (g) * 4]); \
    n0 = ld(ia.x); n1 = ld(ia.y); n2 = ld(ia.z); n3 = ld(ia.w); }

#define CONSA(q, wt) { \
    aA0[0] += wt * bf2f((ushort)q[0]); aA0[1] += wt * bf2f((ushort)q[1]); \
    aA0[2] += wt * bf2f((ushort)q[2]); aA0[3] += wt * bf2f((ushort)q[3]); \
    aA1[0] += wt * bf2f((ushort)q[4]); aA1[1] += wt * bf2f((ushort)q[5]); \
    aA1[2] += wt * bf2f((ushort)q[6]); aA1[3] += wt * bf2f((ushort)q[7]); }
#define CONSB(q, wt) { \
    aB0[0] += wt * bf2f((ushort)q[0]); aB0[1] += wt * bf2f((ushort)q[1]); \
    aB0[2] += wt * bf2f((ushort)q[2]); aB0[3] += wt * bf2f((ushort)q[3]); \
    aB1[0] += wt * bf2f((ushort)q[4]); aB1[1] += wt * bf2f((ushort)q[5]); \
    aB1[2] += wt * bf2f((ushort)q[6]); aB1[3] += wt * bf2f((ushort)q[7]); }

  LOADG(0);
  #pragma unroll
  for (int g = 0; g < 8; ++g) {
    s16x8 q0 = n0, q1 = n1, q2 = n2, q3 = n3;
    float4 va = wa;
    if (g < 7) LOADG(g + 1);
    CONSA(q0, va.x); CONSB(q1, va.y); CONSA(q2, va.z); CONSB(q3, va.w);
  }
#undef LOADG
#undef CONSA
#undef CONSB

  // add self term, GELU
  s16x8 hv = *reinterpret_cast<const s16x8*>(hs + (size_t)m * Hh + l5 * 8);
  float g[8];
  #pragma unroll
  for (int j = 0; j < 4; ++j) {
    g[j]     = gelu_t(aA0[j] + aB0[j] + bf2f((ushort)hv[j]));
    g[j + 4] = gelu_t(aA1[j] + aB1[j] + bf2f((ushort)hv[j + 4]));
  }

  float sv = 0.f, qv = 0.f;
  #pragma unroll
  for (int j = 0; j < 8; ++j) { sv += g[j]; qv += g[j] * g[j]; }
  #pragma unroll
  for (int msk = 16; msk >= 1; msk >>= 1) {   // reduce within the 32-lane half
    sv += __shfl_xor(sv, msk, 64);
    qv += __shfl_xor(qv, msk, 64);
  }
  float mean = sv * (1.0f / 256.0f);
  float var  = qv * (1.0f / 256.0f) - mean * mean;
  float inv  = rsqrtf(var + 1e-5f);

  float4 gm0 = reinterpret_cast<const float4*>(gamma)[l5 * 2];
  float4 gm1 = reinterpret_cast<const float4*>(gamma)[l5 * 2 + 1];
  float4 bt0 = reinterpret_cast<const float4*>(beta)[l5 * 2];
  float4 bt1 = reinterpret_cast<const float4*>(beta)[l5 * 2 + 1];
  float4 o0, o1;
  o0.x = (g[0] - mean) * inv * gm0.x + bt0.x;
  o0.y = (g[1] - mean) * inv * gm0.y + bt0.y;
  o0.z = (g[2] - mean) * inv * gm0.z + bt0.z;
  o0.w = (g[3] - mean) * inv * gm0.w + bt0.w;
  o1.x = (g[4] - mean) * inv * gm1.x + bt1.x;
  o1.y = (g[5] - mean) * inv * gm1.y + bt1.y;
  o1.z = (g[6] - mean) * inv * gm1.z + bt1.z;
  o1.w = (g[7] - mean) * inv * gm1.w + bt1.w;
  float4* op = reinterpret_cast<float4*>(out + (size_t)m * Hh + l5 * 8);
  op[0] = o0;
  op[1] = o1;
}

extern "C" void kernel_launch(void* const* d_in, const int* in_sizes, int n_in,
                              void* d_out, int out_size, void* d_ws, size_t ws_size,
                              hipStream_t stream) {
  const float* h     = (const float*)d_in[0];
  const void*  idx   = d_in[1];
  const float* w     = (const float*)d_in[2];
  const float* Ws    = (const float*)d_in[3];
  const float* Wn    = (const float*)d_in[4];
  const float* gamma = (const float*)d_in[5];
  const float* beta  = (const float*)d_in[6];
  float* out = (float*)d_out;

  ushort* hs = (ushort*)d_ws;                       // 16 MB
  ushort* hn = hs + (size_t)Mm * Hh;                // 16 MB
  ushort* Wc = hn + (size_t)Mm * Hh;                // 256 KB
  int* flag  = (int*)(Wc + 512 * 256);

  detect_idx<<<1, 64, 0, stream>>>((const int*)idx, flag);
  prep_w<<<128, 256, 0, stream>>>(Ws, Wn, Wc);
  gemm1<<<1024, 512, 0, stream>>>(h, Wc, hs, hn);
  k2<<<2048, 512, 0, stream>>>(hs, hn, idx, w, gamma, beta, out, flag);
}

// Round 8
// 59.282 us; speedup vs baseline: 2.0302x; 1.3084x over previous
//
#include <hip/hip_runtime.h>
#include <hip/hip_bf16.h>
#include <math.h>
#include <stdint.h>

constexpr int Nn = 4096, Kk = 32, Hh = 256;
constexpr int Mm = 8 * Nn;          // 32768 rows

typedef float  f32x4 __attribute__((ext_vector_type(4)));
typedef short  s16x8 __attribute__((ext_vector_type(8)));

static __device__ __forceinline__ ushort f2bf(float f) {
  uint32_t u = __float_as_uint(f);
  u += 0x7FFF + ((u >> 16) & 1);
  return (ushort)(u >> 16);
}
static __device__ __forceinline__ float bf2f(ushort s) {
  return __uint_as_float(((uint32_t)s) << 16);
}
static __device__ __forceinline__ void gl_lds16(const ushort* g, ushort* l) {
  __builtin_amdgcn_global_load_lds(
      (const __attribute__((address_space(1))) void*)g,
      (__attribute__((address_space(3))) void*)l, 16, 0, 0);
}
// gelu(x) ~= x - x/(e^y + 1),  y = x*(2c + 2c*0.044715*x^2), c = 0.79788456
static __device__ __forceinline__ float gelu_t(float x) {
  float u = x * x;
  float y = x * (1.5957691216f + 0.0713548162726f * u);
  float t = __expf(y);
  return x - x * __builtin_amdgcn_rcpf(t + 1.0f);
}

// ---------------- idx dtype detector ----------------
__global__ void detect_idx(const int* __restrict__ p, int* __restrict__ flag) {
  int t = threadIdx.x;
  unsigned long long b = __ballot(p[2 * t + 1] != 0);
  if (t == 0) *flag = (b != 0ULL) ? 1 : 0;  // 1 = int32, 0 = int64
}

// ---------------- prep: Wcat = [Ws; Wn] bf16, row-major [512][256] ----------
__global__ __launch_bounds__(256) void prep_w(const float* __restrict__ Ws,
                                              const float* __restrict__ Wn,
                                              ushort* __restrict__ Wc) {
  int i = blockIdx.x * 256 + threadIdx.x;      // 32768 threads, 4 elems each
  int j  = i >> 6;
  int k4 = i & 63;
  const float* src = (j < 256) ? (Ws + (size_t)j * 256 + k4 * 4)
                               : (Wn + (size_t)(j - 256) * 256 + k4 * 4);
  float4 v = *reinterpret_cast<const float4*>(src);
  ushort4 o = { f2bf(v.x), f2bf(v.y), f2bf(v.z), f2bf(v.w) };
  reinterpret_cast<ushort4*>(Wc)[i] = o;
}

// ---------------- gemm1: [hs|hn] = h @ Wcat^T, bf16 out, no epilogue -------
__global__ __launch_bounds__(512, 4) void gemm1(const float* __restrict__ h,
                                                const ushort* __restrict__ Wc,
                                                ushort* __restrict__ hs,
                                                ushort* __restrict__ hn) {
  __shared__ ushort lA[2][64 * 64];    // 2 x 8 KB
  __shared__ ushort lB[2][256 * 64];   // 2 x 32 KB
  const int tid = threadIdx.x, wid = tid >> 6, lane = tid & 63;
  const int wr = wid >> 1, wc = wid & 1;

  const int blk = blockIdx.x;
  const int b = blk & 7, t = blk >> 3;
  const int nblk = t & 1, mblk = t >> 1;
  const int m0 = b * Nn + mblk * 64;
  const ushort* Wbase = Wc + (size_t)nblk * 256 * 256;

  f32x4 acc[8];
  #pragma unroll
  for (int j = 0; j < 8; ++j) acc[j] = f32x4{0.f, 0.f, 0.f, 0.f};

  float4 a0, a1;
  const int ar = tid >> 3, as = tid & 7;             // A stage: row, slot
  auto aload = [&](int kt) {
    const float* src = h + (size_t)(m0 + ar) * 256 + kt * 64 + as * 8;
    a0 = *reinterpret_cast<const float4*>(src);
    a1 = *reinterpret_cast<const float4*>(src + 4);
  };
  auto awrite = [&](int buf) {
    s16x8 u = { (short)f2bf(a0.x), (short)f2bf(a0.y), (short)f2bf(a0.z),
                (short)f2bf(a0.w), (short)f2bf(a1.x), (short)f2bf(a1.y),
                (short)f2bf(a1.z), (short)f2bf(a1.w) };
    *reinterpret_cast<s16x8*>(&lA[buf][ar * 64 + ((as ^ (ar & 7)) << 3)]) = u;
  };
  auto bstage = [&](int buf, int kt) {
    #pragma unroll
    for (int c = 0; c < 4; ++c) {
      int ch = wid + c * 8;
      int r = ch * 8 + (lane >> 3);
      int s = (lane & 7) ^ (r & 7);
      gl_lds16(Wbase + (size_t)r * 256 + kt * 64 + s * 8, &lB[buf][ch * 512]);
    }
  };

  aload(0);
  bstage(0, 0);
  awrite(0);
  __syncthreads();

  int buf = 0;
  for (int kt = 0; kt < 4; ++kt) {
    if (kt < 3) { aload(kt + 1); bstage(buf ^ 1, kt + 1); }
    #pragma unroll
    for (int kk = 0; kk < 2; ++kk) {
      const int ks = kk * 4 + (lane >> 4);
      const int ra = wr * 16 + (lane & 15);
      s16x8 af = *reinterpret_cast<const s16x8*>(
          &lA[buf][ra * 64 + ((ks ^ (ra & 7)) << 3)]);
      s16x8 bfr[8];
      #pragma unroll
      for (int nj = 0; nj < 8; ++nj) {
        int rb = wc * 128 + nj * 16 + (lane & 15);
        bfr[nj] = *reinterpret_cast<const s16x8*>(
            &lB[buf][rb * 64 + ((ks ^ (rb & 7)) << 3)]);
      }
      #pragma unroll
      for (int nj = 0; nj < 8; ++nj)
        acc[nj] = __builtin_amdgcn_mfma_f32_16x16x32_bf16(af, bfr[nj],
                                                          acc[nj], 0, 0, 0);
    }
    if (kt < 3) awrite(buf ^ 1);
    __syncthreads();
    buf ^= 1;
  }

  ushort* dst = (nblk == 0) ? hs : hn;
  #pragma unroll
  for (int nj = 0; nj < 8; ++nj)
    #pragma unroll
    for (int jj = 0; jj < 4; ++jj) {
      int row = wr * 16 + (lane >> 4) * 4 + jj;
      int col = wc * 128 + nj * 16 + (lane & 15);
      dst[(size_t)(m0 + row) * 256 + col] = f2bf(acc[nj][jj]);
    }
}

// ---------------- k2: out = LN(gelu(hs[m] + sum_k w * hn[idx_k])) ----------
// R4-proven base (grid 2048 x 512 thr, 16 rows/blk, row per 32-lane half-wave,
// &7 batch map, shfl metadata, early epilogue loads, dual acc banks).
// SINGLE change vs R4: gather prefetch depth 4 -> 8 (named registers).
__global__ __launch_bounds__(512, 4) void k2(const ushort* __restrict__ hs,
                                             const ushort* __restrict__ hn,
                                             const void* __restrict__ idx,
                                             const float* __restrict__ w,
                                             const float* __restrict__ gamma,
                                             const float* __restrict__ beta,
                                             float* __restrict__ out,
                                             const int* __restrict__ flag) {
  const int tid = threadIdx.x, wv = tid >> 6, lane = tid & 63;
  const int hw = lane >> 5, l5 = lane & 31;
  const int b = blockIdx.x & 7;                       // batch -> XCD pin
  const int m = b * Nn + (blockIdx.x >> 3) * 16 + wv * 2 + hw;
  const int is32 = *flag;

  size_t kb = (size_t)m * Kk + l5;                    // lane l5 owns idx/w[k=l5]
  int   myi = is32 ? ((const int*)idx)[kb] : (int)((const long long*)idx)[kb];
  float myw = w[kb];

  // early long-latency loads (consumed only in the epilogue)
  s16x8 hv = *reinterpret_cast<const s16x8*>(hs + (size_t)m * Hh + l5 * 8);
  float4 gm0 = reinterpret_cast<const float4*>(gamma)[l5 * 2];
  float4 gm1 = reinterpret_cast<const float4*>(gamma)[l5 * 2 + 1];
  float4 bt0 = reinterpret_cast<const float4*>(beta)[l5 * 2];
  float4 bt1 = reinterpret_cast<const float4*>(beta)[l5 * 2 + 1];

  const ushort* hnb = hn + (size_t)b * Nn * Hh;

  auto ld = [&](int k) -> s16x8 {
    int r = __shfl(myi, k, 32);
    return *reinterpret_cast<const s16x8*>(hnb + ((size_t)r << 8) + (l5 << 3));
  };

  f32x4 aA0{0,0,0,0}, aA1{0,0,0,0}, aB0{0,0,0,0}, aB1{0,0,0,0};

#define CONSA(q, wt) { \
    aA0[0] += wt * bf2f((ushort)q[0]); aA0[1] += wt * bf2f((ushort)q[1]); \
    aA0[2] += wt * bf2f((ushort)q[2]); aA0[3] += wt * bf2f((ushort)q[3]); \
    aA1[0] += wt * bf2f((ushort)q[4]); aA1[1] += wt * bf2f((ushort)q[5]); \
    aA1[2] += wt * bf2f((ushort)q[6]); aA1[3] += wt * bf2f((ushort)q[7]); }
#define CONSB(q, wt) { \
    aB0[0] += wt * bf2f((ushort)q[0]); aB0[1] += wt * bf2f((ushort)q[1]); \
    aB0[2] += wt * bf2f((ushort)q[2]); aB0[3] += wt * bf2f((ushort)q[3]); \
    aB1[0] += wt * bf2f((ushort)q[4]); aB1[1] += wt * bf2f((ushort)q[5]); \
    aB1[2] += wt * bf2f((ushort)q[6]); aB1[3] += wt * bf2f((ushort)q[7]); }

  s16x8 p0 = ld(0), p1 = ld(1), p2 = ld(2), p3 = ld(3);
  s16x8 p4 = ld(4), p5 = ld(5), p6 = ld(6), p7 = ld(7);

  #pragma unroll
  for (int k = 0; k < 32; k += 8) {
    float w0 = __shfl(myw, k, 32),     w1 = __shfl(myw, k + 1, 32);
    float w2 = __shfl(myw, k + 2, 32), w3 = __shfl(myw, k + 3, 32);
    float w4 = __shfl(myw, k + 4, 32), w5 = __shfl(myw, k + 5, 32);
    float w6 = __shfl(myw, k + 6, 32), w7 = __shfl(myw, k + 7, 32);
    s16x8 q0 = p0, q1 = p1, q2 = p2, q3 = p3;
    s16x8 q4 = p4, q5 = p5, q6 = p6, q7 = p7;
    if (k + 8 < 32) {
      p0 = ld(k + 8);  p1 = ld(k + 9);  p2 = ld(k + 10); p3 = ld(k + 11);
      p4 = ld(k + 12); p5 = ld(k + 13); p6 = ld(k + 14); p7 = ld(k + 15);
    }
    CONSA(q0, w0); CONSB(q1, w1); CONSA(q2, w2); CONSB(q3, w3);
    CONSA(q4, w4); CONSB(q5, w5); CONSA(q6, w6); CONSB(q7, w7);
  }
#undef CONSA
#undef CONSB

  // add self term, GELU
  float g[8];
  #pragma unroll
  for (int j = 0; j < 4; ++j) {
    g[j]     = gelu_t(aA0[j] + aB0[j] + bf2f((ushort)hv[j]));
    g[j + 4] = gelu_t(aA1[j] + aB1[j] + bf2f((ushort)hv[j + 4]));
  }

  float sv = 0.f, qv = 0.f;
  #pragma unroll
  for (int j = 0; j < 8; ++j) { sv += g[j]; qv += g[j] * g[j]; }
  #pragma unroll
  for (int msk = 16; msk >= 1; msk >>= 1) {   // reduce within the 32-lane half
    sv += __shfl_xor(sv, msk, 64);
    qv += __shfl_xor(qv, msk, 64);
  }
  float mean = sv * (1.0f / 256.0f);
  float var  = qv * (1.0f / 256.0f) - mean * mean;
  float inv  = rsqrtf(var + 1e-5f);

  float4 o0, o1;
  o0.x = (g[0] - mean) * inv * gm0.x + bt0.x;
  o0.y = (g[1] - mean) * inv * gm0.y + bt0.y;
  o0.z = (g[2] - mean) * inv * gm0.z + bt0.z;
  o0.w = (g[3] - mean) * inv * gm0.w + bt0.w;
  o1.x = (g[4] - mean) * inv * gm1.x + bt1.x;
  o1.y = (g[5] - mean) * inv * gm1.y + bt1.y;
  o1.z = (g[6] - mean) * inv * gm1.z + bt1.z;
  o1.w = (g[7] - mean) * inv * gm1.w + bt1.w;
  float4* op = reinterpret_cast<float4*>(out + (size_t)m * Hh + l5 * 8);
  op[0] = o0;
  op[1] = o1;
}

extern "C" void kernel_launch(void* const* d_in, const int* in_sizes, int n_in,
                              void* d_out, int out_size, void* d_ws, size_t ws_size,
                              hipStream_t stream) {
  const float* h     = (const float*)d_in[0];
  const void*  idx   = d_in[1];
  const float* w     = (const float*)d_in[2];
  const float* Ws    = (const float*)d_in[3];
  const float* Wn    = (const float*)d_in[4];
  const float* gamma = (const float*)d_in[5];
  const float* beta  = (const float*)d_in[6];
  float* out = (float*)d_out;

  ushort* hs = (ushort*)d_ws;                       // 16 MB
  ushort* hn = hs + (size_t)Mm * Hh;                // 16 MB
  ushort* Wc = hn + (size_t)Mm * Hh;                // 256 KB
  int* flag  = (int*)(Wc + 512 * 256);

  detect_idx<<<1, 64, 0, stream>>>((const int*)idx, flag);
  prep_w<<<128, 256, 0, stream>>>(Ws, Wn, Wc);
  gemm1<<<1024, 512, 0, stream>>>(h, Wc, hs, hn);
  k2<<<2048, 512, 0, stream>>>(hs, hn, idx, w, gamma, beta, out, flag);
}

// Round 9
// 58.252 us; speedup vs baseline: 2.0661x; 1.0177x over previous
//
#include <hip/hip_runtime.h>
#include <hip/hip_bf16.h>
#include <math.h>
#include <stdint.h>

constexpr int Nn = 4096, Kk = 32, Hh = 256;
constexpr int Mm = 8 * Nn;          // 32768 rows

typedef float  f32x4 __attribute__((ext_vector_type(4)));
typedef short  s16x8 __attribute__((ext_vector_type(8)));

static __device__ __forceinline__ ushort f2bf(float f) {
  uint32_t u = __float_as_uint(f);
  u += 0x7FFF + ((u >> 16) & 1);
  return (ushort)(u >> 16);
}
static __device__ __forceinline__ float bf2f(ushort s) {
  return __uint_as_float(((uint32_t)s) << 16);
}
static __device__ __forceinline__ void gl_lds16(const ushort* g, ushort* l) {
  __builtin_amdgcn_global_load_lds(
      (const __attribute__((address_space(1))) void*)g,
      (__attribute__((address_space(3))) void*)l, 16, 0, 0);
}
// gelu(x) ~= x - x/(e^y + 1),  y = x*(2c + 2c*0.044715*x^2), c = 0.79788456
static __device__ __forceinline__ float gelu_t(float x) {
  float u = x * x;
  float y = x * (1.5957691216f + 0.0713548162726f * u);
  float t = __expf(y);
  return x - x * __builtin_amdgcn_rcpf(t + 1.0f);
}

// ------- prep: Wcat = [Ws; Wn] bf16 [512][256]; also idx-dtype detect ------
__global__ __launch_bounds__(256) void prep_w(const float* __restrict__ Ws,
                                              const float* __restrict__ Wn,
                                              ushort* __restrict__ Wc,
                                              const int* __restrict__ idxp,
                                              int* __restrict__ flag) {
  if (blockIdx.x == 0 && threadIdx.x < 64) {   // wave 0: int64 high-word test
    unsigned long long bl = __ballot(idxp[2 * threadIdx.x + 1] != 0);
    if (threadIdx.x == 0) *flag = (bl != 0ULL) ? 1 : 0;  // 1=int32, 0=int64
  }
  int i = blockIdx.x * 256 + threadIdx.x;      // 32768 threads, 4 elems each
  int j  = i >> 6;
  int k4 = i & 63;
  const float* src = (j < 256) ? (Ws + (size_t)j * 256 + k4 * 4)
                               : (Wn + (size_t)(j - 256) * 256 + k4 * 4);
  float4 v = *reinterpret_cast<const float4*>(src);
  ushort4 o = { f2bf(v.x), f2bf(v.y), f2bf(v.z), f2bf(v.w) };
  reinterpret_cast<ushort4*>(Wc)[i] = o;
}

// ---------------- gemm1: [hs|hn] = h @ Wcat^T, bf16 out, no epilogue -------
__global__ __launch_bounds__(512, 4) void gemm1(const float* __restrict__ h,
                                                const ushort* __restrict__ Wc,
                                                ushort* __restrict__ hs,
                                                ushort* __restrict__ hn) {
  __shared__ ushort lA[2][64 * 64];    // 2 x 8 KB
  __shared__ ushort lB[2][256 * 64];   // 2 x 32 KB
  const int tid = threadIdx.x, wid = tid >> 6, lane = tid & 63;
  const int wr = wid >> 1, wc = wid & 1;

  const int blk = blockIdx.x;
  const int b = blk & 7, t = blk >> 3;
  const int nblk = t & 1, mblk = t >> 1;
  const int m0 = b * Nn + mblk * 64;
  const ushort* Wbase = Wc + (size_t)nblk * 256 * 256;

  f32x4 acc[8];
  #pragma unroll
  for (int j = 0; j < 8; ++j) acc[j] = f32x4{0.f, 0.f, 0.f, 0.f};

  float4 a0, a1;
  const int ar = tid >> 3, as = tid & 7;             // A stage: row, slot
  auto aload = [&](int kt) {
    const float* src = h + (size_t)(m0 + ar) * 256 + kt * 64 + as * 8;
    a0 = *reinterpret_cast<const float4*>(src);
    a1 = *reinterpret_cast<const float4*>(src + 4);
  };
  auto awrite = [&](int buf) {
    s16x8 u = { (short)f2bf(a0.x), (short)f2bf(a0.y), (short)f2bf(a0.z),
                (short)f2bf(a0.w), (short)f2bf(a1.x), (short)f2bf(a1.y),
                (short)f2bf(a1.z), (short)f2bf(a1.w) };
    *reinterpret_cast<s16x8*>(&lA[buf][ar * 64 + ((as ^ (ar & 7)) << 3)]) = u;
  };
  auto bstage = [&](int buf, int kt) {
    #pragma unroll
    for (int c = 0; c < 4; ++c) {
      int ch = wid + c * 8;
      int r = ch * 8 + (lane >> 3);
      int s = (lane & 7) ^ (r & 7);
      gl_lds16(Wbase + (size_t)r * 256 + kt * 64 + s * 8, &lB[buf][ch * 512]);
    }
  };

  aload(0);
  bstage(0, 0);
  awrite(0);
  __syncthreads();

  int buf = 0;
  for (int kt = 0; kt < 4; ++kt) {
    if (kt < 3) { aload(kt + 1); bstage(buf ^ 1, kt + 1); }
    #pragma unroll
    for (int kk = 0; kk < 2; ++kk) {
      const int ks = kk * 4 + (lane >> 4);
      const int ra = wr * 16 + (lane & 15);
      s16x8 af = *reinterpret_cast<const s16x8*>(
          &lA[buf][ra * 64 + ((ks ^ (ra & 7)) << 3)]);
      s16x8 bfr[8];
      #pragma unroll
      for (int nj = 0; nj < 8; ++nj) {
        int rb = wc * 128 + nj * 16 + (lane & 15);
        bfr[nj] = *reinterpret_cast<const s16x8*>(
            &lB[buf][rb * 64 + ((ks ^ (rb & 7)) << 3)]);
      }
      #pragma unroll
      for (int nj = 0; nj < 8; ++nj)
        acc[nj] = __builtin_amdgcn_mfma_f32_16x16x32_bf16(af, bfr[nj],
                                                          acc[nj], 0, 0, 0);
    }
    if (kt < 3) awrite(buf ^ 1);
    __syncthreads();
    buf ^= 1;
  }

  ushort* dst = (nblk == 0) ? hs : hn;
  #pragma unroll
  for (int nj = 0; nj < 8; ++nj)
    #pragma unroll
    for (int jj = 0; jj < 4; ++jj) {
      int row = wr * 16 + (lane >> 4) * 4 + jj;
      int col = wc * 128 + nj * 16 + (lane & 15);
      dst[(size_t)(m0 + row) * 256 + col] = f2bf(acc[nj][jj]);
    }
}

// ---------------- k2: out = LN(gelu(hs[m] + sum_k w * hn[idx_k])) ----------
// R4-proven base (grid 2048 x 512 thr, 16 rows/blk, row per 32-lane half-wave,
// &7 batch map, early epilogue loads, depth-4 prefetch, dual acc banks).
// SINGLE change vs R4: all 32 idx shuffles + byte-offset calc hoisted out of
// the loop into a fully-unrolled register array -> loads issue with uniform
// base + precomputed 32-bit offset, no shfl/addr chain per gather group.
__global__ __launch_bounds__(512, 4) void k2(const ushort* __restrict__ hs,
                                             const ushort* __restrict__ hn,
                                             const void* __restrict__ idx,
                                             const float* __restrict__ w,
                                             const float* __restrict__ gamma,
                                             const float* __restrict__ beta,
                                             float* __restrict__ out,
                                             const int* __restrict__ flag) {
  const int tid = threadIdx.x, wv = tid >> 6, lane = tid & 63;
  const int hw = lane >> 5, l5 = lane & 31;
  const int b = blockIdx.x & 7;                       // batch -> XCD pin
  const int m = b * Nn + (blockIdx.x >> 3) * 16 + wv * 2 + hw;
  const int is32 = *flag;

  size_t kb = (size_t)m * Kk + l5;                    // lane l5 owns idx/w[k=l5]
  int   myi = is32 ? ((const int*)idx)[kb] : (int)((const long long*)idx)[kb];
  float myw = w[kb];

  // early long-latency loads (consumed only in the epilogue)
  s16x8 hv = *reinterpret_cast<const s16x8*>(hs + (size_t)m * Hh + l5 * 8);
  float4 gm0 = reinterpret_cast<const float4*>(gamma)[l5 * 2];
  float4 gm1 = reinterpret_cast<const float4*>(gamma)[l5 * 2 + 1];
  float4 bt0 = reinterpret_cast<const float4*>(beta)[l5 * 2];
  float4 bt1 = reinterpret_cast<const float4*>(beta)[l5 * 2 + 1];

  const char* hnb = (const char*)(hn + (size_t)b * Nn * Hh);
  const int lb = l5 << 4;                             // lane byte offset in row

  // hoisted: all 32 row broadcasts -> byte offsets (register array, all
  // accesses at compile-time indices via full unroll)
  int o[32];
  #pragma unroll
  for (int k = 0; k < 32; ++k)
    o[k] = (__shfl(myi, k, 32) << 9) + lb;

  f32x4 aA0{0,0,0,0}, aA1{0,0,0,0}, aB0{0,0,0,0}, aB1{0,0,0,0};

#define LD(k) (*reinterpret_cast<const s16x8*>(hnb + o[k]))
#define CONSA(q, wt) { \
    aA0[0] += wt * bf2f((ushort)q[0]); aA0[1] += wt * bf2f((ushort)q[1]); \
    aA0[2] += wt * bf2f((ushort)q[2]); aA0[3] += wt * bf2f((ushort)q[3]); \
    aA1[0] += wt * bf2f((ushort)q[4]); aA1[1] += wt * bf2f((ushort)q[5]); \
    aA1[2] += wt * bf2f((ushort)q[6]); aA1[3] += wt * bf2f((ushort)q[7]); }
#define CONSB(q, wt) { \
    aB0[0] += wt * bf2f((ushort)q[0]); aB0[1] += wt * bf2f((ushort)q[1]); \
    aB0[2] += wt * bf2f((ushort)q[2]); aB0[3] += wt * bf2f((ushort)q[3]); \
    aB1[0] += wt * bf2f((ushort)q[4]); aB1[1] += wt * bf2f((ushort)q[5]); \
    aB1[2] += wt * bf2f((ushort)q[6]); aB1[3] += wt * bf2f((ushort)q[7]); }

  s16x8 p0 = LD(0), p1 = LD(1), p2 = LD(2), p3 = LD(3);

  #pragma unroll
  for (int k = 0; k < 32; k += 4) {
    float w0 = __shfl(myw, k, 32),     w1 = __shfl(myw, k + 1, 32);
    float w2 = __shfl(myw, k + 2, 32), w3 = __shfl(myw, k + 3, 32);
    s16x8 q0 = p0, q1 = p1, q2 = p2, q3 = p3;
    if (k + 4 < 32) {
      p0 = LD(k + 4); p1 = LD(k + 5); p2 = LD(k + 6); p3 = LD(k + 7);
    }
    CONSA(q0, w0); CONSB(q1, w1); CONSA(q2, w2); CONSB(q3, w3);
  }
#undef LD
#undef CONSA
#undef CONSB

  // add self term, GELU
  float g[8];
  #pragma unroll
  for (int j = 0; j < 4; ++j) {
    g[j]     = gelu_t(aA0[j] + aB0[j] + bf2f((ushort)hv[j]));
    g[j + 4] = gelu_t(aA1[j] + aB1[j] + bf2f((ushort)hv[j + 4]));
  }

  float sv = 0.f, qv = 0.f;
  #pragma unroll
  for (int j = 0; j < 8; ++j) { sv += g[j]; qv += g[j] * g[j]; }
  #pragma unroll
  for (int msk = 16; msk >= 1; msk >>= 1) {   // reduce within the 32-lane half
    sv += __shfl_xor(sv, msk, 64);
    qv += __shfl_xor(qv, msk, 64);
  }
  float mean = sv * (1.0f / 256.0f);
  float var  = qv * (1.0f / 256.0f) - mean * mean;
  float inv  = rsqrtf(var + 1e-5f);

  float4 o0, o1;
  o0.x = (g[0] - mean) * inv * gm0.x + bt0.x;
  o0.y = (g[1] - mean) * inv * gm0.y + bt0.y;
  o0.z = (g[2] - mean) * inv * gm0.z + bt0.z;
  o0.w = (g[3] - mean) * inv * gm0.w + bt0.w;
  o1.x = (g[4] - mean) * inv * gm1.x + bt1.x;
  o1.y = (g[5] - mean) * inv * gm1.y + bt1.y;
  o1.z = (g[6] - mean) * inv * gm1.z + bt1.z;
  o1.w = (g[7] - mean) * inv * gm1.w + bt1.w;
  float4* op = reinterpret_cast<float4*>(out + (size_t)m * Hh + l5 * 8);
  op[0] = o0;
  op[1] = o1;
}

extern "C" void kernel_launch(void* const* d_in, const int* in_sizes, int n_in,
                              void* d_out, int out_size, void* d_ws, size_t ws_size,
                              hipStream_t stream) {
  const float* h     = (const float*)d_in[0];
  const void*  idx   = d_in[1];
  const float* w     = (const float*)d_in[2];
  const float* Ws    = (const float*)d_in[3];
  const float* Wn    = (const float*)d_in[4];
  const float* gamma = (const float*)d_in[5];
  const float* beta  = (const float*)d_in[6];
  float* out = (float*)d_out;

  ushort* hs = (ushort*)d_ws;                       // 16 MB
  ushort* hn = hs + (size_t)Mm * Hh;                // 16 MB
  ushort* Wc = hn + (size_t)Mm * Hh;                // 256 KB
  int* flag  = (int*)(Wc + 512 * 256);

  prep_w<<<128, 256, 0, stream>>>(Ws, Wn, Wc, (const int*)idx, flag);
  gemm1<<<1024, 512, 0, stream>>>(h, Wc, hs, hn);
  k2<<<2048, 512, 0, stream>>>(hs, hn, idx, w, gamma, beta, out, flag);
}